// Round 1
// 413.870 us; speedup vs baseline: 1.1817x; 1.1817x over previous
//
#include <hip/hip_runtime.h>

#define T_TOK 4096
#define H_DIM 2048
#define I_DIM 768
#define E_NUM 8

typedef __attribute__((ext_vector_type(8))) short bf16x8;
typedef __attribute__((ext_vector_type(4))) float f32x4;

__device__ __forceinline__ unsigned short f2bf(float f) {
  union { float f; unsigned int u; } c; c.f = f;
  unsigned int r = c.u + 0x7fffu + ((c.u >> 16) & 1u);
  return (unsigned short)(r >> 16);
}

// async global->LDS DMA, 16B per lane; lds dest = wave-uniform base + lane*16
__device__ __forceinline__ void gl_lds16(const unsigned short* g, unsigned short* l) {
  __builtin_amdgcn_global_load_lds(
      (const __attribute__((address_space(1))) unsigned int*)g,
      (__attribute__((address_space(3))) unsigned int*)l, 16, 0, 0);
}

// ---------------- weights: f32 [E][K][N] -> bf16 [E][N][K] ----------------
__global__ __launch_bounds__(256) void transpose_cast_kernel(
    const float* __restrict__ src, unsigned short* __restrict__ dst,
    int K, int N)
{
  const int e = blockIdx.z;
  const int kb = blockIdx.y * 64, nb = blockIdx.x * 64;
  src += (size_t)e * K * N + (size_t)kb * N + nb;
  dst += (size_t)e * N * K + (size_t)nb * K + kb;
  __shared__ float tile[64][65];
  const int tid = threadIdx.x;
  const int lr = tid >> 4, lc = (tid & 15) * 4;
#pragma unroll
  for (int it = 0; it < 4; ++it) {
    float4 v = *(const float4*)(src + (size_t)(lr + it * 16) * N + lc);
    tile[lr + it * 16][lc]     = v.x;
    tile[lr + it * 16][lc + 1] = v.y;
    tile[lr + it * 16][lc + 2] = v.z;
    tile[lr + it * 16][lc + 3] = v.w;
  }
  __syncthreads();
  const int wn = tid >> 2, wk = (tid & 3) * 16;
  union { uint4 u[2]; unsigned short h[16]; } o;
#pragma unroll
  for (int j = 0; j < 16; ++j) o.h[j] = f2bf(tile[wk + j][wn]);
  *(uint4*)(dst + (size_t)wn * K + wk)     = o.u[0];
  *(uint4*)(dst + (size_t)wn * K + wk + 8) = o.u[1];
}

// ---------------- Router (+ fused x f32->bf16 cast) ----------------
// v2: 8 tokens per block, w_router slice cached in registers, block-aggregated
// atomics (<=8 per block instead of 2 dependent per token).
#define RTOK 8
__global__ __launch_bounds__(256) void router_kernel(
    const float* __restrict__ x,               // [T,H] f32
    const float* __restrict__ wr,              // [H,E] f32
    unsigned short* __restrict__ xbf,          // [T,H] bf16 out
    float* __restrict__ logits_out,            // [T,E] f32 (d_out tail)
    int* __restrict__ counts,                  // [E]
    int* __restrict__ entries,                 // [E][T] pair-slot p = t*2+k
    float* __restrict__ entry_w)               // [E][T]
{
  const int tid = threadIdx.x;
  const int w = tid >> 6, lane = tid & 63;
  const int t0 = blockIdx.x * RTOK;
  const int hb = w * 512 + lane * 8;           // this thread's H-chunk base

  // cache this thread's 8 rows x 8 experts of w_router in registers (64 VGPR)
  float wreg[8][8];
#pragma unroll
  for (int r = 0; r < 8; ++r) {
    *(float4*)&wreg[r][0] = *(const float4*)(wr + (size_t)(hb + r) * E_NUM);
    *(float4*)&wreg[r][4] = *(const float4*)(wr + (size_t)(hb + r) * E_NUM + 4);
  }

  __shared__ float red[RTOK][4][E_NUM];        // wave partials
  __shared__ float lg[RTOK][E_NUM];            // logits
  __shared__ int   ch_i[RTOK][2];
  __shared__ float ch_w[RTOK][2];

  for (int tt = 0; tt < RTOK; ++tt) {
    const int t = t0 + tt;
    float xv[8];
    *(float4*)&xv[0] = *(const float4*)(x + (size_t)t * H_DIM + hb);
    *(float4*)&xv[4] = *(const float4*)(x + (size_t)t * H_DIM + hb + 4);
    // fused cast of this x chunk to bf16 (16B/lane, fully coalesced)
    union { uint4 u; unsigned short h[8]; } o;
#pragma unroll
    for (int j = 0; j < 8; ++j) o.h[j] = f2bf(xv[j]);
    *(uint4*)(xbf + (size_t)t * H_DIM + hb) = o.u;

    float acc[E_NUM];
#pragma unroll
    for (int e = 0; e < E_NUM; ++e) acc[e] = 0.f;
#pragma unroll
    for (int r = 0; r < 8; ++r)
#pragma unroll
      for (int e = 0; e < E_NUM; ++e) acc[e] = fmaf(xv[r], wreg[r][e], acc[e]);
#pragma unroll
    for (int off = 32; off > 0; off >>= 1)
#pragma unroll
      for (int e = 0; e < E_NUM; ++e) acc[e] += __shfl_down(acc[e], off);
    if (lane == 0)
#pragma unroll
      for (int e = 0; e < E_NUM; ++e) red[tt][w][e] = acc[e];
  }
  __syncthreads();

  // 64 threads: finish logits (sum 4 wave partials), write logits_out
  if (tid < RTOK * E_NUM) {
    const int tt = tid >> 3, e = tid & 7;
    float l = red[tt][0][e] + red[tt][1][e] + red[tt][2][e] + red[tt][3][e];
    lg[tt][e] = l;
    logits_out[(size_t)(t0 + tt) * E_NUM + e] = l;
  }
  __syncthreads();

  // 8 threads: top-2 per token
  if (tid < RTOK) {
    const int tt = tid;
    float m1 = lg[tt][0]; int i1 = 0;
#pragma unroll
    for (int e = 1; e < E_NUM; ++e) if (lg[tt][e] > m1) { m1 = lg[tt][e]; i1 = e; }
    float m2 = -3.4e38f; int i2 = -1;
#pragma unroll
    for (int e = 0; e < E_NUM; ++e) if (e != i1 && lg[tt][e] > m2) { m2 = lg[tt][e]; i2 = e; }
    float w1 = 1.f / (1.f + __expf(m2 - m1));
    ch_i[tt][0] = i1; ch_i[tt][1] = i2;
    ch_w[tt][0] = w1; ch_w[tt][1] = 1.f - w1;
  }
  __syncthreads();

  // 8 threads (one per expert): aggregate block's pairs, ONE atomic per expert
  if (tid < E_NUM) {
    const int e = tid;
    int cnt = 0;
#pragma unroll
    for (int tt = 0; tt < RTOK; ++tt) {
      if (ch_i[tt][0] == e) ++cnt;
      if (ch_i[tt][1] == e) ++cnt;
    }
    if (cnt > 0) {
      int base = atomicAdd(&counts[e], cnt);
      int pos = 0;
#pragma unroll
      for (int tt = 0; tt < RTOK; ++tt) {
#pragma unroll
        for (int k = 0; k < 2; ++k) {
          if (ch_i[tt][k] == e) {
            entries[e * T_TOK + base + pos] = (t0 + tt) * 2 + k;
            entry_w[e * T_TOK + base + pos] = ch_w[tt][k];
            ++pos;
          }
        }
      }
    }
  }
}

// Fragment read from XOR-swizzled flat tile: row stride 64 shorts, chunk of 8
// physical chunk = logical ^ (row & 7)
#define FRAG(arr, row, cb) \
  (*(const bf16x8*)(&(arr)[((row) << 6) + ((((cb)) ^ ((row) & 7)) << 3)]))

// ---------------- Up-projection: act[p,:] = silu(x Wg) * (x Wu) ----------------
// BM=128, BN=64, BK=64. Weights pre-transposed bf16 [E][I][H]. DMA staging.
__global__ __launch_bounds__(256) void moe_up_kernel(
    const unsigned short* __restrict__ xbf,   // [T,H] bf16
    const unsigned short* __restrict__ wgt,   // [E][I][H] bf16
    const unsigned short* __restrict__ wut,   // [E][I][H] bf16
    const int* __restrict__ counts,
    const int* __restrict__ entries,
    unsigned short* __restrict__ act)         // [2T, I] bf16
{
  const int e = blockIdx.z;
  const int cnt = counts[e];
  const int m0 = blockIdx.y * 128;
  if (m0 >= cnt) return;
  const int n0 = blockIdx.x * 64;
  const int tid = threadIdx.x;

  __shared__ __align__(16) unsigned short As[128 * 64];
  __shared__ __align__(16) unsigned short Bg[64 * 64];
  __shared__ __align__(16) unsigned short Bu[64 * 64];
  __shared__ int rowp[128];

  if (tid < 128) rowp[tid] = (m0 + tid < cnt) ? entries[e * T_TOK + m0 + tid] : -1;
  __syncthreads();

  const int w = tid >> 6, lane = tid & 63;
  const int lrow = lane >> 3, lchunk = lane & 7;
  const int jj = lchunk ^ lrow;              // swizzled global chunk (lane-const)

  // Per-round source pointers (advance by kt inside loop)
  const unsigned short* wg_e = wgt + (size_t)e * I_DIM * H_DIM + (size_t)n0 * H_DIM;
  const unsigned short* wu_e = wut + (size_t)e * I_DIM * H_DIM + (size_t)n0 * H_DIM;
  const unsigned short* gA[4];
  unsigned short* lA[4];
#pragma unroll
  for (int t4 = 0; t4 < 4; ++t4) {
    int r = (t4 * 4 + w) * 8 + lrow;         // 0..127
    int p = rowp[r];
    int tok = (p >= 0) ? (p >> 1) : 0;
    gA[t4] = xbf + (size_t)tok * H_DIM + jj * 8;
    lA[t4] = As + (t4 * 4 + w) * 512;        // 8 rows * 64 shorts
  }
  const unsigned short* gG[2]; const unsigned short* gU[2]; unsigned short* lG[2]; unsigned short* lU[2];
#pragma unroll
  for (int t2 = 0; t2 < 2; ++t2) {
    int r = (t2 * 4 + w) * 8 + lrow;         // 0..63
    gG[t2] = wg_e + (size_t)r * H_DIM + jj * 8;
    gU[t2] = wu_e + (size_t)r * H_DIM + jj * 8;
    lG[t2] = Bg + (t2 * 4 + w) * 512;
    lU[t2] = Bu + (t2 * 4 + w) * 512;
  }

  f32x4 accg[4][2], accu[4][2];
#pragma unroll
  for (int i = 0; i < 4; ++i)
#pragma unroll
    for (int j = 0; j < 2; ++j) {
      accg[i][j] = (f32x4){0.f, 0.f, 0.f, 0.f};
      accu[i][j] = (f32x4){0.f, 0.f, 0.f, 0.f};
    }

  const int msub = (w >> 1) * 64, nsub = (w & 1) * 32;
  const int fm = lane & 15, fq = lane >> 4;
  const int f7 = fm & 7;

  for (int kt = 0; kt < H_DIM; kt += 64) {
#pragma unroll
    for (int t4 = 0; t4 < 4; ++t4) gl_lds16(gA[t4] + kt, lA[t4]);
#pragma unroll
    for (int t2 = 0; t2 < 2; ++t2) {
      gl_lds16(gG[t2] + kt, lG[t2]);
      gl_lds16(gU[t2] + kt, lU[t2]);
    }
    __syncthreads();
#pragma unroll
    for (int ks = 0; ks < 64; ks += 32) {
      const int cb = (ks >> 3) + fq;
      bf16x8 a[4], bg[2], bu[2];
#pragma unroll
      for (int mi = 0; mi < 4; ++mi)
        a[mi] = FRAG(As, msub + mi * 16 + fm, cb);
#pragma unroll
      for (int ni = 0; ni < 2; ++ni) {
        bg[ni] = FRAG(Bg, nsub + ni * 16 + fm, cb);
        bu[ni] = FRAG(Bu, nsub + ni * 16 + fm, cb);
      }
#pragma unroll
      for (int mi = 0; mi < 4; ++mi)
#pragma unroll
        for (int ni = 0; ni < 2; ++ni) {
          accg[mi][ni] = __builtin_amdgcn_mfma_f32_16x16x32_bf16(a[mi], bg[ni], accg[mi][ni], 0, 0, 0);
          accu[mi][ni] = __builtin_amdgcn_mfma_f32_16x16x32_bf16(a[mi], bu[ni], accu[mi][ni], 0, 0, 0);
        }
    }
    __syncthreads();
  }
#pragma unroll
  for (int mi = 0; mi < 4; ++mi) {
#pragma unroll
    for (int r = 0; r < 4; ++r) {
      int ml = msub + mi * 16 + fq * 4 + r;
      int p = rowp[ml];
      if (p < 0) continue;
      size_t base = (size_t)p * I_DIM + n0 + nsub + fm;
#pragma unroll
      for (int ni = 0; ni < 2; ++ni) {
        float g = accg[mi][ni][r];
        float u = accu[mi][ni][r];
        float h = g / (1.f + __expf(-g)) * u;
        act[base + ni * 16] = f2bf(h);
      }
    }
  }
}

// ---------------- Down-projection + weighted scatter-add into d_out ----------------
// BM=128, BN=128, BK=64. wot pre-transposed bf16 [E][H][I]. DMA staging.
__global__ __launch_bounds__(256) void moe_down_kernel(
    const unsigned short* __restrict__ act,   // [2T, I] bf16
    const unsigned short* __restrict__ wot,   // [E][H][I] bf16
    const int* __restrict__ counts,
    const int* __restrict__ entries,
    const float* __restrict__ entry_w,
    float* __restrict__ out)                  // [T,H] f32
{
  const int e = blockIdx.z;
  const int cnt = counts[e];
  const int m0 = blockIdx.y * 128;
  if (m0 >= cnt) return;
  const int n0 = blockIdx.x * 128;
  const int tid = threadIdx.x;

  __shared__ __align__(16) unsigned short As[128 * 64];
  __shared__ __align__(16) unsigned short Bt[128 * 64];
  __shared__ int rowp[128];
  __shared__ float roww[128];

  if (tid < 128) {
    int idx = m0 + tid;
    rowp[tid] = (idx < cnt) ? entries[e * T_TOK + idx] : -1;
    roww[tid] = (idx < cnt) ? entry_w[e * T_TOK + idx] : 0.f;
  }
  __syncthreads();

  const int w = tid >> 6, lane = tid & 63;
  const int lrow = lane >> 3, lchunk = lane & 7;
  const int jj = lchunk ^ lrow;

  const unsigned short* wo_e = wot + (size_t)e * H_DIM * I_DIM + (size_t)n0 * I_DIM;
  const unsigned short* gA[4]; unsigned short* lA[4];
  const unsigned short* gB[4]; unsigned short* lB[4];
#pragma unroll
  for (int t4 = 0; t4 < 4; ++t4) {
    int r = (t4 * 4 + w) * 8 + lrow;
    int p = rowp[r];
    int pr = (p >= 0) ? p : 0;
    gA[t4] = act + (size_t)pr * I_DIM + jj * 8;
    lA[t4] = As + (t4 * 4 + w) * 512;
    gB[t4] = wo_e + (size_t)r * I_DIM + jj * 8;
    lB[t4] = Bt + (t4 * 4 + w) * 512;
  }

  f32x4 acc[4][4];
#pragma unroll
  for (int i = 0; i < 4; ++i)
#pragma unroll
    for (int j = 0; j < 4; ++j) acc[i][j] = (f32x4){0.f, 0.f, 0.f, 0.f};

  const int msub = (w >> 1) * 64, nsub = (w & 1) * 64;
  const int fm = lane & 15, fq = lane >> 4;

  for (int kt = 0; kt < I_DIM; kt += 64) {
#pragma unroll
    for (int t4 = 0; t4 < 4; ++t4) {
      gl_lds16(gA[t4] + kt, lA[t4]);
      gl_lds16(gB[t4] + kt, lB[t4]);
    }
    __syncthreads();
#pragma unroll
    for (int ks = 0; ks < 64; ks += 32) {
      const int cb = (ks >> 3) + fq;
      bf16x8 a[4], b[4];
#pragma unroll
      for (int mi = 0; mi < 4; ++mi)
        a[mi] = FRAG(As, msub + mi * 16 + fm, cb);
#pragma unroll
      for (int ni = 0; ni < 4; ++ni)
        b[ni] = FRAG(Bt, nsub + ni * 16 + fm, cb);
#pragma unroll
      for (int mi = 0; mi < 4; ++mi)
#pragma unroll
        for (int ni = 0; ni < 4; ++ni)
          acc[mi][ni] = __builtin_amdgcn_mfma_f32_16x16x32_bf16(a[mi], b[ni], acc[mi][ni], 0, 0, 0);
    }
    __syncthreads();
  }
#pragma unroll
  for (int mi = 0; mi < 4; ++mi) {
#pragma unroll
    for (int r = 0; r < 4; ++r) {
      int ml = msub + mi * 16 + fq * 4 + r;
      int p = rowp[ml];
      if (p < 0) continue;
      float wt = roww[ml];
      float* dst = out + (size_t)(p >> 1) * H_DIM + n0 + nsub + fm;
#pragma unroll
      for (int ni = 0; ni < 4; ++ni)
        atomicAdd(dst + ni * 16, acc[mi][ni][r] * wt);
    }
  }
}

extern "C" void kernel_launch(void* const* d_in, const int* in_sizes, int n_in,
                              void* d_out, int out_size, void* d_ws, size_t ws_size,
                              hipStream_t stream) {
  const float* x   = (const float*)d_in[0];
  const float* wr  = (const float*)d_in[1];
  const float* wi0 = (const float*)d_in[2];
  const float* wi1 = (const float*)d_in[3];
  const float* wo  = (const float*)d_in[4];
  float* out = (float*)d_out;                       // [T,H] f32
  float* logits_out = out + (size_t)T_TOK * H_DIM;  // [T,E] f32

  char* w = (char*)d_ws;
  int* counts    = (int*)w;                                          // 64 B
  int* entries   = (int*)(w + 64);                                   // 128 KB
  float* entry_w = (float*)(w + 64 + (size_t)E_NUM * T_TOK * 4);     // 128 KB
  size_t off = 64 + 2 * (size_t)E_NUM * T_TOK * 4;
  unsigned short* xbf = (unsigned short*)(w + off); off += (size_t)T_TOK * H_DIM * 2;
  unsigned short* wgt = (unsigned short*)(w + off); off += (size_t)E_NUM * H_DIM * I_DIM * 2;
  unsigned short* wut = (unsigned short*)(w + off); off += (size_t)E_NUM * H_DIM * I_DIM * 2;
  unsigned short* wot = (unsigned short*)(w + off); off += (size_t)E_NUM * H_DIM * I_DIM * 2;
  unsigned short* act = (unsigned short*)(w + off);                  // [2T, I] bf16

  hipMemsetAsync(d_out, 0, (size_t)T_TOK * H_DIM * sizeof(float), stream);
  hipMemsetAsync(counts, 0, 64, stream);
  transpose_cast_kernel<<<dim3(I_DIM / 64, H_DIM / 64, E_NUM), 256, 0, stream>>>(
      wi0, wgt, H_DIM, I_DIM);
  transpose_cast_kernel<<<dim3(I_DIM / 64, H_DIM / 64, E_NUM), 256, 0, stream>>>(
      wi1, wut, H_DIM, I_DIM);
  transpose_cast_kernel<<<dim3(H_DIM / 64, I_DIM / 64, E_NUM), 256, 0, stream>>>(
      wo, wot, I_DIM, H_DIM);
  router_kernel<<<T_TOK / RTOK, 256, 0, stream>>>(x, wr, xbf, logits_out, counts, entries, entry_w);
  moe_up_kernel<<<dim3(I_DIM / 64, T_TOK / 128, E_NUM), 256, 0, stream>>>(
      xbf, wgt, wut, counts, entries, act);
  moe_down_kernel<<<dim3(H_DIM / 128, T_TOK / 128, E_NUM), 256, 0, stream>>>(
      act, wot, counts, entries, entry_w, out);
}

// Round 2
// 410.335 us; speedup vs baseline: 1.1919x; 1.0086x over previous
//
#include <hip/hip_runtime.h>

#define T_TOK 4096
#define H_DIM 2048
#define I_DIM 768
#define E_NUM 8

typedef __attribute__((ext_vector_type(8))) short bf16x8;
typedef __attribute__((ext_vector_type(4))) float f32x4;

__device__ __forceinline__ unsigned short f2bf(float f) {
  union { float f; unsigned int u; } c; c.f = f;
  unsigned int r = c.u + 0x7fffu + ((c.u >> 16) & 1u);
  return (unsigned short)(r >> 16);
}

// async global->LDS DMA, 16B per lane; lds dest = wave-uniform base + lane*16
__device__ __forceinline__ void gl_lds16(const unsigned short* g, unsigned short* l) {
  __builtin_amdgcn_global_load_lds(
      (const __attribute__((address_space(1))) unsigned int*)g,
      (__attribute__((address_space(3))) unsigned int*)l, 16, 0, 0);
}

// ---------------- weights: f32 [E][K][N] -> bf16 [E][N][K] ----------------
__global__ __launch_bounds__(256) void transpose_cast_kernel(
    const float* __restrict__ src, unsigned short* __restrict__ dst,
    int K, int N)
{
  const int e = blockIdx.z;
  const int kb = blockIdx.y * 64, nb = blockIdx.x * 64;
  src += (size_t)e * K * N + (size_t)kb * N + nb;
  dst += (size_t)e * N * K + (size_t)nb * K + kb;
  __shared__ float tile[64][65];
  const int tid = threadIdx.x;
  const int lr = tid >> 4, lc = (tid & 15) * 4;
#pragma unroll
  for (int it = 0; it < 4; ++it) {
    float4 v = *(const float4*)(src + (size_t)(lr + it * 16) * N + lc);
    tile[lr + it * 16][lc]     = v.x;
    tile[lr + it * 16][lc + 1] = v.y;
    tile[lr + it * 16][lc + 2] = v.z;
    tile[lr + it * 16][lc + 3] = v.w;
  }
  __syncthreads();
  const int wn = tid >> 2, wk = (tid & 3) * 16;
  union { uint4 u[2]; unsigned short h[16]; } o;
#pragma unroll
  for (int j = 0; j < 16; ++j) o.h[j] = f2bf(tile[wk + j][wn]);
  *(uint4*)(dst + (size_t)wn * K + wk)     = o.u[0];
  *(uint4*)(dst + (size_t)wn * K + wk + 8) = o.u[1];
}

// ---------------- Router (+ fused x f32->bf16 cast) ----------------
// 8 tokens per block, w_router slice cached in registers, block-aggregated
// atomics (<=8 per block instead of 2 dependent per token).
#define RTOK 8
__global__ __launch_bounds__(256) void router_kernel(
    const float* __restrict__ x,               // [T,H] f32
    const float* __restrict__ wr,              // [H,E] f32
    unsigned short* __restrict__ xbf,          // [T,H] bf16 out
    float* __restrict__ logits_out,            // [T,E] f32 (d_out tail)
    int* __restrict__ counts,                  // [E]
    int* __restrict__ entries,                 // [E][T] pair-slot p = t*2+k
    float* __restrict__ entry_w)               // [E][T]
{
  const int tid = threadIdx.x;
  const int w = tid >> 6, lane = tid & 63;
  const int t0 = blockIdx.x * RTOK;
  const int hb = w * 512 + lane * 8;           // this thread's H-chunk base

  // cache this thread's 8 rows x 8 experts of w_router in registers (64 VGPR)
  float wreg[8][8];
#pragma unroll
  for (int r = 0; r < 8; ++r) {
    *(float4*)&wreg[r][0] = *(const float4*)(wr + (size_t)(hb + r) * E_NUM);
    *(float4*)&wreg[r][4] = *(const float4*)(wr + (size_t)(hb + r) * E_NUM + 4);
  }

  __shared__ float red[RTOK][4][E_NUM];        // wave partials
  __shared__ float lg[RTOK][E_NUM];            // logits
  __shared__ int   ch_i[RTOK][2];
  __shared__ float ch_w[RTOK][2];

  for (int tt = 0; tt < RTOK; ++tt) {
    const int t = t0 + tt;
    float xv[8];
    *(float4*)&xv[0] = *(const float4*)(x + (size_t)t * H_DIM + hb);
    *(float4*)&xv[4] = *(const float4*)(x + (size_t)t * H_DIM + hb + 4);
    // fused cast of this x chunk to bf16 (16B/lane, fully coalesced)
    union { uint4 u; unsigned short h[8]; } o;
#pragma unroll
    for (int j = 0; j < 8; ++j) o.h[j] = f2bf(xv[j]);
    *(uint4*)(xbf + (size_t)t * H_DIM + hb) = o.u;

    float acc[E_NUM];
#pragma unroll
    for (int e = 0; e < E_NUM; ++e) acc[e] = 0.f;
#pragma unroll
    for (int r = 0; r < 8; ++r)
#pragma unroll
      for (int e = 0; e < E_NUM; ++e) acc[e] = fmaf(xv[r], wreg[r][e], acc[e]);
#pragma unroll
    for (int off = 32; off > 0; off >>= 1)
#pragma unroll
      for (int e = 0; e < E_NUM; ++e) acc[e] += __shfl_down(acc[e], off);
    if (lane == 0)
#pragma unroll
      for (int e = 0; e < E_NUM; ++e) red[tt][w][e] = acc[e];
  }
  __syncthreads();

  // 64 threads: finish logits (sum 4 wave partials), write logits_out
  if (tid < RTOK * E_NUM) {
    const int tt = tid >> 3, e = tid & 7;
    float l = red[tt][0][e] + red[tt][1][e] + red[tt][2][e] + red[tt][3][e];
    lg[tt][e] = l;
    logits_out[(size_t)(t0 + tt) * E_NUM + e] = l;
  }
  __syncthreads();

  // 8 threads: top-2 per token
  if (tid < RTOK) {
    const int tt = tid;
    float m1 = lg[tt][0]; int i1 = 0;
#pragma unroll
    for (int e = 1; e < E_NUM; ++e) if (lg[tt][e] > m1) { m1 = lg[tt][e]; i1 = e; }
    float m2 = -3.4e38f; int i2 = -1;
#pragma unroll
    for (int e = 0; e < E_NUM; ++e) if (e != i1 && lg[tt][e] > m2) { m2 = lg[tt][e]; i2 = e; }
    float w1 = 1.f / (1.f + __expf(m2 - m1));
    ch_i[tt][0] = i1; ch_i[tt][1] = i2;
    ch_w[tt][0] = w1; ch_w[tt][1] = 1.f - w1;
  }
  __syncthreads();

  // 8 threads (one per expert): aggregate block's pairs, ONE atomic per expert
  if (tid < E_NUM) {
    const int e = tid;
    int cnt = 0;
#pragma unroll
    for (int tt = 0; tt < RTOK; ++tt) {
      if (ch_i[tt][0] == e) ++cnt;
      if (ch_i[tt][1] == e) ++cnt;
    }
    if (cnt > 0) {
      int base = atomicAdd(&counts[e], cnt);
      int pos = 0;
#pragma unroll
      for (int tt = 0; tt < RTOK; ++tt) {
#pragma unroll
        for (int k = 0; k < 2; ++k) {
          if (ch_i[tt][k] == e) {
            entries[e * T_TOK + base + pos] = (t0 + tt) * 2 + k;
            entry_w[e * T_TOK + base + pos] = ch_w[tt][k];
            ++pos;
          }
        }
      }
    }
  }
}

// Fragment read from XOR-swizzled flat tile: row stride 64 shorts, chunk of 8
// physical chunk = logical ^ (row & 7)
#define FRAG(arr, row, cb) \
  (*(const bf16x8*)(&(arr)[((row) << 6) + ((((cb)) ^ ((row) & 7)) << 3)]))

// ---------------- Up-projection: act[p,:] = silu(x Wg) * (x Wu) ----------------
// BM=128, BN=64, BK=64. Weights pre-transposed bf16 [E][I][H]. DMA staging.
// v3: double-buffered LDS, prefetch-next-before-compute, 1 barrier per K-step
// (T3 minimum-2-phase). Hides ~900cy HBM latency under the MFMA phase.
__global__ __launch_bounds__(256) void moe_up_kernel(
    const unsigned short* __restrict__ xbf,   // [T,H] bf16
    const unsigned short* __restrict__ wgt,   // [E][I][H] bf16
    const unsigned short* __restrict__ wut,   // [E][I][H] bf16
    const int* __restrict__ counts,
    const int* __restrict__ entries,
    unsigned short* __restrict__ act)         // [2T, I] bf16
{
  const int e = blockIdx.z;
  const int cnt = counts[e];
  const int m0 = blockIdx.y * 128;
  if (m0 >= cnt) return;
  const int n0 = blockIdx.x * 64;
  const int tid = threadIdx.x;

  __shared__ __align__(16) unsigned short As[2][128 * 64];
  __shared__ __align__(16) unsigned short Bg[2][64 * 64];
  __shared__ __align__(16) unsigned short Bu[2][64 * 64];
  __shared__ int rowp[128];

  if (tid < 128) rowp[tid] = (m0 + tid < cnt) ? entries[e * T_TOK + m0 + tid] : -1;
  __syncthreads();

  const int w = tid >> 6, lane = tid & 63;
  const int lrow = lane >> 3, lchunk = lane & 7;
  const int jj = lchunk ^ lrow;              // swizzled global chunk (lane-const)

  const unsigned short* wg_e = wgt + (size_t)e * I_DIM * H_DIM + (size_t)n0 * H_DIM;
  const unsigned short* wu_e = wut + (size_t)e * I_DIM * H_DIM + (size_t)n0 * H_DIM;
  const unsigned short* gA[4];
  int aoff[4];
#pragma unroll
  for (int t4 = 0; t4 < 4; ++t4) {
    int r = (t4 * 4 + w) * 8 + lrow;         // 0..127
    int p = rowp[r];
    int tok = (p >= 0) ? (p >> 1) : 0;
    gA[t4] = xbf + (size_t)tok * H_DIM + jj * 8;
    aoff[t4] = (t4 * 4 + w) * 512;           // 8 rows * 64 shorts
  }
  const unsigned short* gG[2]; const unsigned short* gU[2];
  int boff[2];
#pragma unroll
  for (int t2 = 0; t2 < 2; ++t2) {
    int r = (t2 * 4 + w) * 8 + lrow;         // 0..63
    gG[t2] = wg_e + (size_t)r * H_DIM + jj * 8;
    gU[t2] = wu_e + (size_t)r * H_DIM + jj * 8;
    boff[t2] = (t2 * 4 + w) * 512;
  }

  f32x4 accg[4][2], accu[4][2];
#pragma unroll
  for (int i = 0; i < 4; ++i)
#pragma unroll
    for (int j = 0; j < 2; ++j) {
      accg[i][j] = (f32x4){0.f, 0.f, 0.f, 0.f};
      accu[i][j] = (f32x4){0.f, 0.f, 0.f, 0.f};
    }

  const int msub = (w >> 1) * 64, nsub = (w & 1) * 32;
  const int fm = lane & 15, fq = lane >> 4;

  // prologue: stage tile 0 into buf 0
#pragma unroll
  for (int t4 = 0; t4 < 4; ++t4) gl_lds16(gA[t4], &As[0][aoff[t4]]);
#pragma unroll
  for (int t2 = 0; t2 < 2; ++t2) {
    gl_lds16(gG[t2], &Bg[0][boff[t2]]);
    gl_lds16(gU[t2], &Bu[0][boff[t2]]);
  }
  __syncthreads();                            // drains vmcnt(0) + barrier

  int cur = 0;
  for (int kt = 0; kt < H_DIM; kt += 64) {
    const int nxt = cur ^ 1;
    if (kt + 64 < H_DIM) {                    // prefetch next tile (issues only)
#pragma unroll
      for (int t4 = 0; t4 < 4; ++t4) gl_lds16(gA[t4] + kt + 64, &As[nxt][aoff[t4]]);
#pragma unroll
      for (int t2 = 0; t2 < 2; ++t2) {
        gl_lds16(gG[t2] + kt + 64, &Bg[nxt][boff[t2]]);
        gl_lds16(gU[t2] + kt + 64, &Bu[nxt][boff[t2]]);
      }
    }
    const unsigned short* Ac  = As[cur];
    const unsigned short* Bgc = Bg[cur];
    const unsigned short* Buc = Bu[cur];
#pragma unroll
    for (int ks = 0; ks < 64; ks += 32) {
      const int cb = (ks >> 3) + fq;
      bf16x8 a[4], bg[2], bu[2];
#pragma unroll
      for (int mi = 0; mi < 4; ++mi)
        a[mi] = FRAG(Ac, msub + mi * 16 + fm, cb);
#pragma unroll
      for (int ni = 0; ni < 2; ++ni) {
        bg[ni] = FRAG(Bgc, nsub + ni * 16 + fm, cb);
        bu[ni] = FRAG(Buc, nsub + ni * 16 + fm, cb);
      }
#pragma unroll
      for (int mi = 0; mi < 4; ++mi)
#pragma unroll
        for (int ni = 0; ni < 2; ++ni) {
          accg[mi][ni] = __builtin_amdgcn_mfma_f32_16x16x32_bf16(a[mi], bg[ni], accg[mi][ni], 0, 0, 0);
          accu[mi][ni] = __builtin_amdgcn_mfma_f32_16x16x32_bf16(a[mi], bu[ni], accu[mi][ni], 0, 0, 0);
        }
    }
    __syncthreads();                          // prefetch landed; reads done
    cur = nxt;
  }
#pragma unroll
  for (int mi = 0; mi < 4; ++mi) {
#pragma unroll
    for (int r = 0; r < 4; ++r) {
      int ml = msub + mi * 16 + fq * 4 + r;
      int p = rowp[ml];
      if (p < 0) continue;
      size_t base = (size_t)p * I_DIM + n0 + nsub + fm;
#pragma unroll
      for (int ni = 0; ni < 2; ++ni) {
        float g = accg[mi][ni][r];
        float u = accu[mi][ni][r];
        float h = g / (1.f + __expf(-g)) * u;
        act[base + ni * 16] = f2bf(h);
      }
    }
  }
}

// ---------------- Down-projection + weighted scatter-add into d_out ----------------
// BM=128, BN=128, BK=64. wot pre-transposed bf16 [E][H][I]. DMA staging.
// v3: same double-buffered prefetch structure as moe_up.
__global__ __launch_bounds__(256) void moe_down_kernel(
    const unsigned short* __restrict__ act,   // [2T, I] bf16
    const unsigned short* __restrict__ wot,   // [E][H][I] bf16
    const int* __restrict__ counts,
    const int* __restrict__ entries,
    const float* __restrict__ entry_w,
    float* __restrict__ out)                  // [T,H] f32
{
  const int e = blockIdx.z;
  const int cnt = counts[e];
  const int m0 = blockIdx.y * 128;
  if (m0 >= cnt) return;
  const int n0 = blockIdx.x * 128;
  const int tid = threadIdx.x;

  __shared__ __align__(16) unsigned short As[2][128 * 64];
  __shared__ __align__(16) unsigned short Bt[2][128 * 64];
  __shared__ int rowp[128];
  __shared__ float roww[128];

  if (tid < 128) {
    int idx = m0 + tid;
    rowp[tid] = (idx < cnt) ? entries[e * T_TOK + idx] : -1;
    roww[tid] = (idx < cnt) ? entry_w[e * T_TOK + idx] : 0.f;
  }
  __syncthreads();

  const int w = tid >> 6, lane = tid & 63;
  const int lrow = lane >> 3, lchunk = lane & 7;
  const int jj = lchunk ^ lrow;

  const unsigned short* wo_e = wot + (size_t)e * H_DIM * I_DIM + (size_t)n0 * I_DIM;
  const unsigned short* gA[4]; const unsigned short* gB[4];
  int off4[4];
#pragma unroll
  for (int t4 = 0; t4 < 4; ++t4) {
    int r = (t4 * 4 + w) * 8 + lrow;
    int p = rowp[r];
    int pr = (p >= 0) ? p : 0;
    gA[t4] = act + (size_t)pr * I_DIM + jj * 8;
    gB[t4] = wo_e + (size_t)r * I_DIM + jj * 8;
    off4[t4] = (t4 * 4 + w) * 512;
  }

  f32x4 acc[4][4];
#pragma unroll
  for (int i = 0; i < 4; ++i)
#pragma unroll
    for (int j = 0; j < 4; ++j) acc[i][j] = (f32x4){0.f, 0.f, 0.f, 0.f};

  const int msub = (w >> 1) * 64, nsub = (w & 1) * 64;
  const int fm = lane & 15, fq = lane >> 4;

  // prologue: stage tile 0 into buf 0
#pragma unroll
  for (int t4 = 0; t4 < 4; ++t4) {
    gl_lds16(gA[t4], &As[0][off4[t4]]);
    gl_lds16(gB[t4], &Bt[0][off4[t4]]);
  }
  __syncthreads();

  int cur = 0;
  for (int kt = 0; kt < I_DIM; kt += 64) {
    const int nxt = cur ^ 1;
    if (kt + 64 < I_DIM) {
#pragma unroll
      for (int t4 = 0; t4 < 4; ++t4) {
        gl_lds16(gA[t4] + kt + 64, &As[nxt][off4[t4]]);
        gl_lds16(gB[t4] + kt + 64, &Bt[nxt][off4[t4]]);
      }
    }
    const unsigned short* Ac = As[cur];
    const unsigned short* Bc = Bt[cur];
#pragma unroll
    for (int ks = 0; ks < 64; ks += 32) {
      const int cb = (ks >> 3) + fq;
      bf16x8 a[4], b[4];
#pragma unroll
      for (int mi = 0; mi < 4; ++mi)
        a[mi] = FRAG(Ac, msub + mi * 16 + fm, cb);
#pragma unroll
      for (int ni = 0; ni < 4; ++ni)
        b[ni] = FRAG(Bc, nsub + ni * 16 + fm, cb);
#pragma unroll
      for (int mi = 0; mi < 4; ++mi)
#pragma unroll
        for (int ni = 0; ni < 4; ++ni)
          acc[mi][ni] = __builtin_amdgcn_mfma_f32_16x16x32_bf16(a[mi], b[ni], acc[mi][ni], 0, 0, 0);
    }
    __syncthreads();
    cur = nxt;
  }
#pragma unroll
  for (int mi = 0; mi < 4; ++mi) {
#pragma unroll
    for (int r = 0; r < 4; ++r) {
      int ml = msub + mi * 16 + fq * 4 + r;
      int p = rowp[ml];
      if (p < 0) continue;
      float wt = roww[ml];
      float* dst = out + (size_t)(p >> 1) * H_DIM + n0 + nsub + fm;
#pragma unroll
      for (int ni = 0; ni < 4; ++ni)
        atomicAdd(dst + ni * 16, acc[mi][ni][r] * wt);
    }
  }
}

extern "C" void kernel_launch(void* const* d_in, const int* in_sizes, int n_in,
                              void* d_out, int out_size, void* d_ws, size_t ws_size,
                              hipStream_t stream) {
  const float* x   = (const float*)d_in[0];
  const float* wr  = (const float*)d_in[1];
  const float* wi0 = (const float*)d_in[2];
  const float* wi1 = (const float*)d_in[3];
  const float* wo  = (const float*)d_in[4];
  float* out = (float*)d_out;                       // [T,H] f32
  float* logits_out = out + (size_t)T_TOK * H_DIM;  // [T,E] f32

  char* w = (char*)d_ws;
  int* counts    = (int*)w;                                          // 64 B
  int* entries   = (int*)(w + 64);                                   // 128 KB
  float* entry_w = (float*)(w + 64 + (size_t)E_NUM * T_TOK * 4);     // 128 KB
  size_t off = 64 + 2 * (size_t)E_NUM * T_TOK * 4;
  unsigned short* xbf = (unsigned short*)(w + off); off += (size_t)T_TOK * H_DIM * 2;
  unsigned short* wgt = (unsigned short*)(w + off); off += (size_t)E_NUM * H_DIM * I_DIM * 2;
  unsigned short* wut = (unsigned short*)(w + off); off += (size_t)E_NUM * H_DIM * I_DIM * 2;
  unsigned short* wot = (unsigned short*)(w + off); off += (size_t)E_NUM * H_DIM * I_DIM * 2;
  unsigned short* act = (unsigned short*)(w + off);                  // [2T, I] bf16

  hipMemsetAsync(d_out, 0, (size_t)T_TOK * H_DIM * sizeof(float), stream);
  hipMemsetAsync(counts, 0, 64, stream);
  transpose_cast_kernel<<<dim3(I_DIM / 64, H_DIM / 64, E_NUM), 256, 0, stream>>>(
      wi0, wgt, H_DIM, I_DIM);
  transpose_cast_kernel<<<dim3(I_DIM / 64, H_DIM / 64, E_NUM), 256, 0, stream>>>(
      wi1, wut, H_DIM, I_DIM);
  transpose_cast_kernel<<<dim3(H_DIM / 64, I_DIM / 64, E_NUM), 256, 0, stream>>>(
      wo, wot, I_DIM, H_DIM);
  router_kernel<<<T_TOK / RTOK, 256, 0, stream>>>(x, wr, xbf, logits_out, counts, entries, entry_w);
  moe_up_kernel<<<dim3(I_DIM / 64, T_TOK / 128, E_NUM), 256, 0, stream>>>(
      xbf, wgt, wut, counts, entries, act);
  moe_down_kernel<<<dim3(H_DIM / 128, T_TOK / 128, E_NUM), 256, 0, stream>>>(
      act, wot, counts, entries, entry_w, out);
}